// Round 1
// baseline (82.335 us; speedup 1.0000x reference)
//
#include <hip/hip_runtime.h>

#define SEG 64
#define TPB 256

struct DA { float d, a; };

__device__ __forceinline__ DA da_compose(DA f, DA g) {
    // apply f first, then g:  c -> c*f.d + f.a -> (c*f.d + f.a)*g.d + g.a
    DA r; r.d = f.d * g.d; r.a = fmaf(f.a, g.d, g.a); return r;
}

// ---------------- Phase 1: per-segment (D,A) + per-block aggregate ----------------
__global__ void __launch_bounds__(TPB) hawkes_phase1(
    const float* __restrict__ ts, const float* __restrict__ lb_p,
    const int* __restrict__ T_p, int N, int NSEG,
    DA* __restrict__ segDA, DA* __restrict__ blkDA)
{
    const float beta = __expf(*lb_p);
    const int tid = threadIdx.x;
    const int g = blockIdx.x * TPB + tid;

    DA my; my.d = 1.f; my.a = 0.f;
    if (g < NSEG) {
        const int start = g * SEG;
        const int end = min(start + SEG, N);
        const float Tf = (float)(*T_p);
        const float rnext = (end < N) ? ts[end] : Tf;
        float R, t0, tprev;
        if (end == start + SEG) {
            const float4* p = (const float4*)(ts + start);
            float4 v = p[0];
            t0 = v.x; tprev = t0; R = 1.f;
            { float e = __expf(-beta * (v.y - tprev)); R = fmaf(R, e, 1.f); tprev = v.y; }
            { float e = __expf(-beta * (v.z - tprev)); R = fmaf(R, e, 1.f); tprev = v.z; }
            { float e = __expf(-beta * (v.w - tprev)); R = fmaf(R, e, 1.f); tprev = v.w; }
            #pragma unroll
            for (int q = 1; q < SEG / 4; ++q) {
                float4 w4 = p[q];
                { float e = __expf(-beta * (w4.x - tprev)); R = fmaf(R, e, 1.f); tprev = w4.x; }
                { float e = __expf(-beta * (w4.y - tprev)); R = fmaf(R, e, 1.f); tprev = w4.y; }
                { float e = __expf(-beta * (w4.z - tprev)); R = fmaf(R, e, 1.f); tprev = w4.z; }
                { float e = __expf(-beta * (w4.w - tprev)); R = fmaf(R, e, 1.f); tprev = w4.w; }
            }
        } else {
            t0 = ts[start]; tprev = t0; R = 1.f;
            for (int j = start + 1; j < end; ++j) {
                float t = ts[j];
                float e = __expf(-beta * (t - tprev)); R = fmaf(R, e, 1.f); tprev = t;
            }
        }
        my.a = R * __expf(-beta * (rnext - tprev));
        my.d = __expf(-beta * (rnext - t0));
        segDA[g] = my;
    }

    // order-preserving tree reduce of the 256 segment compositions
    __shared__ DA lds[TPB];
    lds[tid] = my;
    __syncthreads();
    #pragma unroll
    for (int s = 1; s < TPB; s <<= 1) {
        if ((tid & (2 * s - 1)) == 0) lds[tid] = da_compose(lds[tid], lds[tid + s]);
        __syncthreads();
    }
    if (tid == 0) blkDA[blockIdx.x] = lds[0];
}

// ---------------- Phase 2: scan block aggregates -> per-block carries + S(T) ----------------
__global__ void __launch_bounds__(TPB) hawkes_phase2(
    const DA* __restrict__ blkDA, int NB,
    float* __restrict__ blkCarry, float* __restrict__ stats /* [0] = S(T) */,
    double* __restrict__ acc)
{
    const int tid = threadIdx.x;
    if (tid == 0) *acc = 0.0;   // ws is poisoned each call; zero here (runs before phase3)

    const int K2 = (NB + TPB - 1) / TPB;
    const int b0 = min(tid * K2, NB);
    const int b1 = min(b0 + K2, NB);

    DA comp; comp.d = 1.f; comp.a = 0.f;
    for (int b = b0; b < b1; ++b) comp = da_compose(comp, blkDA[b]);

    const int lane = tid & 63, wave = tid >> 6;
    DA inc = comp;
    #pragma unroll
    for (int off = 1; off < 64; off <<= 1) {
        DA up; up.d = __shfl_up(inc.d, off); up.a = __shfl_up(inc.a, off);
        if (lane >= off) inc = da_compose(up, inc);
    }
    __shared__ DA waveAgg[TPB / 64];
    if (lane == 63) waveAgg[wave] = inc;
    __syncthreads();
    DA pre; pre.d = 1.f; pre.a = 0.f;
    for (int w = 0; w < wave; ++w) pre = da_compose(pre, waveAgg[w]);
    DA lexcl; lexcl.d = __shfl_up(inc.d, 1); lexcl.a = __shfl_up(inc.a, 1);
    if (lane == 0) { lexcl.d = 1.f; lexcl.a = 0.f; }
    DA excl = da_compose(pre, lexcl);

    float c = excl.a;  // initial global carry is 0 -> 0*D + A
    for (int b = b0; b < b1; ++b) {
        blkCarry[b] = c;
        DA x = blkDA[b];
        c = fmaf(c, x.d, x.a);
    }
    if (b0 < NB && b1 == NB) stats[0] = c;  // total decayed sum at time T
}

// ---------------- Phase 3: per-event intensities + log-sum ----------------
__global__ void __launch_bounds__(TPB) hawkes_phase3(
    const float* __restrict__ ts,
    const float* __restrict__ mu_p, const float* __restrict__ la_p,
    const float* __restrict__ lb_p, int N, int NSEG,
    const DA* __restrict__ segDA, const float* __restrict__ blkCarry,
    double* __restrict__ acc)
{
    const float mu = *mu_p;
    const float beta = __expf(*lb_p);
    const float ab = __expf(*la_p) * beta;
    const int tid = threadIdx.x;
    const int g = blockIdx.x * TPB + tid;
    const int lane = tid & 63, wave = tid >> 6;

    DA my; my.d = 1.f; my.a = 0.f;
    if (g < NSEG) my = segDA[g];

    // block-local exclusive scan to get per-thread carry-in
    DA inc = my;
    #pragma unroll
    for (int off = 1; off < 64; off <<= 1) {
        DA up; up.d = __shfl_up(inc.d, off); up.a = __shfl_up(inc.a, off);
        if (lane >= off) inc = da_compose(up, inc);
    }
    __shared__ DA waveAgg[TPB / 64];
    if (lane == 63) waveAgg[wave] = inc;
    __syncthreads();
    DA pre; pre.d = 1.f; pre.a = 0.f;
    for (int w = 0; w < wave; ++w) pre = da_compose(pre, waveAgg[w]);
    DA lexcl; lexcl.d = __shfl_up(inc.d, 1); lexcl.a = __shfl_up(inc.a, 1);
    if (lane == 0) { lexcl.d = 1.f; lexcl.a = 0.f; }
    DA excl = da_compose(pre, lexcl);

    const float bc = blkCarry[blockIdx.x];
    float S = fmaf(bc, excl.d, excl.a);   // S at this thread's first event (exclusive)

    float lsum = 0.f;
    if (g < NSEG) {
        const int start = g * SEG;
        const int end = min(start + SEG, N);
        if (end == start + SEG) {
            const float4* p = (const float4*)(ts + start);
            float4 v = p[0];
            float tprev = v.x;
            lsum += __logf(fmaf(ab, S, mu));
#define HSTEP(tt) { float e = __expf(-beta * ((tt) - tprev)); S = fmaf(S, e, e); \
                    lsum += __logf(fmaf(ab, S, mu)); tprev = (tt); }
            HSTEP(v.y); HSTEP(v.z); HSTEP(v.w);
            #pragma unroll
            for (int q = 1; q < SEG / 4; ++q) {
                float4 w4 = p[q];
                HSTEP(w4.x); HSTEP(w4.y); HSTEP(w4.z); HSTEP(w4.w);
            }
#undef HSTEP
        } else {
            float tprev = ts[start];
            lsum += __logf(fmaf(ab, S, mu));
            for (int j = start + 1; j < end; ++j) {
                float t = ts[j];
                float e = __expf(-beta * (t - tprev));
                S = fmaf(S, e, e);
                lsum += __logf(fmaf(ab, S, mu));
                tprev = t;
            }
        }
    }

    // block reduce lsum -> one double atomic per block
    #pragma unroll
    for (int off = 32; off > 0; off >>= 1) lsum += __shfl_down(lsum, off);
    __shared__ float wsum[TPB / 64];
    if (lane == 0) wsum[wave] = lsum;
    __syncthreads();
    if (tid == 0) {
        float tot = 0.f;
        #pragma unroll
        for (int w = 0; w < TPB / 64; ++w) tot += wsum[w];
        atomicAdd(acc, (double)tot);
    }
}

// ---------------- Phase 4: final assembly ----------------
__global__ void hawkes_phase4(
    const double* __restrict__ acc, const float* __restrict__ stats,
    const float* __restrict__ mu_p, const float* __restrict__ la_p,
    const float* __restrict__ lb_p, const int* __restrict__ T_p,
    int N, float* __restrict__ out)
{
    const float mu = *mu_p;
    const float alpha = __expf(*la_p);
    const float beta = __expf(*lb_p);
    const float Tf = (float)(*T_p);
    const float integral = mu * Tf + (alpha / beta) * ((float)N - stats[0]);
    out[0] = (float)(*acc) - integral;
}

extern "C" void kernel_launch(void* const* d_in, const int* in_sizes, int n_in,
                              void* d_out, int out_size, void* d_ws, size_t ws_size,
                              hipStream_t stream) {
    const float* ts = (const float*)d_in[0];
    const float* mu = (const float*)d_in[1];
    const float* la = (const float*)d_in[2];
    const float* lb = (const float*)d_in[3];
    const int*   T  = (const int*)d_in[4];
    const int N = in_sizes[0];
    const int NSEG = (N + SEG - 1) / SEG;
    const int NB = (NSEG + TPB - 1) / TPB;

    char* w = (char*)d_ws;
    double* acc      = (double*)w;                                   // 8 B
    float*  stats    = (float*)(w + 8);                              // 4 B (S_T)
    DA*     segDA    = (DA*)(w + 16);                                // NSEG * 8 B
    DA*     blkDA    = (DA*)(w + 16 + (size_t)NSEG * sizeof(DA));    // NB * 8 B
    float*  blkCarry = (float*)(w + 16 + (size_t)(NSEG + NB) * sizeof(DA)); // NB * 4 B

    hawkes_phase1<<<NB, TPB, 0, stream>>>(ts, lb, T, N, NSEG, segDA, blkDA);
    hawkes_phase2<<<1, TPB, 0, stream>>>(blkDA, NB, blkCarry, stats, acc);
    hawkes_phase3<<<NB, TPB, 0, stream>>>(ts, mu, la, lb, N, NSEG, segDA, blkCarry, acc);
    hawkes_phase4<<<1, 1, 0, stream>>>(acc, stats, mu, la, lb, T, N, (float*)d_out);
}